// Round 4
// baseline (1310.538 us; speedup 1.0000x reference)
//
#include <hip/hip_runtime.h>

typedef __attribute__((ext_vector_type(8))) short short8v;
typedef __attribute__((ext_vector_type(4))) float float4v;

__device__ __constant__ float c_LO[8] = {
    -0.010597401784997278f, 0.032883011666982945f, 0.030841381835986965f,
    -0.18703481171888114f, -0.02798376941698385f, 0.6308807679295904f,
    0.7148465705525415f, 0.23037781330885523f};
__device__ __constant__ float c_HI[8] = {
    -0.23037781330885523f, 0.7148465705525415f, -0.6308807679295904f,
    -0.02798376941698385f, 0.18703481171888114f, 0.030841381835986965f,
    -0.032883011666982945f, -0.010597401784997278f};

__device__ __forceinline__ unsigned short f2bf(float f) {
    unsigned u = __builtin_bit_cast(unsigned, f);
    unsigned r = u + 0x7fffu + ((u >> 16) & 1u);
    return (unsigned short)(r >> 16);
}
__device__ __forceinline__ float bf2f(unsigned short u) {
    return __builtin_bit_cast(float, (unsigned)u << 16);
}

__device__ __forceinline__ void gload_lds16(const void* g, void* l) {
    __builtin_amdgcn_global_load_lds(g, l, 16, 0, 0);
}

// ---------------- CSR build: histogram ----------------
__global__ void hist_kernel(const int* __restrict__ rows, int* __restrict__ cnt, int E) {
    int i = blockIdx.x * blockDim.x + threadIdx.x;
    if (i < E) atomicAdd(&cnt[rows[i]], 1);
}

// ---------------- CSR build: single-block scan over 16384 counts ----------------
__global__ __launch_bounds__(1024) void scan_kernel(const int* __restrict__ cnt, int* __restrict__ offs,
                                                    int* __restrict__ cursor, int Nrows, int E) {
    __shared__ int part[1024];
    int tid = threadIdx.x;
    const int per = Nrows / 1024;  // 16
    int base = tid * per;
    int local[16];
    int s = 0;
    for (int i = 0; i < per; ++i) { local[i] = s; s += cnt[base + i]; }
    part[tid] = s;
    __syncthreads();
    for (int off = 1; off < 1024; off <<= 1) {
        int v = part[tid];
        int w = (tid >= off) ? part[tid - off] : 0;
        __syncthreads();
        part[tid] = v + w;
        __syncthreads();
    }
    int pre = (tid == 0) ? 0 : part[tid - 1];
    for (int i = 0; i < per; ++i) {
        int o = pre + local[i];
        offs[base + i] = o;
        cursor[base + i] = o;
    }
    if (tid == 0) offs[Nrows] = E;
}

// ---------------- CSR build: scatter ----------------
__global__ void scatter_kernel(const int* __restrict__ rows, const int* __restrict__ cols,
                               const float* __restrict__ vals, int* __restrict__ cursor,
                               int* __restrict__ ccol, float* __restrict__ cval, int E) {
    int i = blockIdx.x * blockDim.x + threadIdx.x;
    if (i >= E) return;
    int r = rows[i];
    int p = atomicAdd(&cursor[r], 1);
    ccol[p] = cols[i];
    cval[p] = vals[i];
}

// ---------------- SpMM CSR: one wave per row, no atomics, D=768 ----------------
__global__ __launch_bounds__(256) void spmm_csr(const float* __restrict__ x, const int* __restrict__ offs,
                                                const int* __restrict__ ccol, const float* __restrict__ cval,
                                                float* __restrict__ xa) {
    int r = blockIdx.x * 4 + (threadIdx.x >> 6);
    int lane = threadIdx.x & 63;
    int s = offs[r], e = offs[r + 1];
    float4 a0 = {0, 0, 0, 0}, a1 = a0, a2 = a0;
    for (int j = s; j < e; ++j) {
        int c = ccol[j];
        float v = cval[j];
        const float* xr = x + (size_t)c * 768;
        float4 v0 = *(const float4*)(xr + lane * 4);
        float4 v1 = *(const float4*)(xr + 256 + lane * 4);
        float4 v2 = *(const float4*)(xr + 512 + lane * 4);
        a0.x = fmaf(v, v0.x, a0.x); a0.y = fmaf(v, v0.y, a0.y);
        a0.z = fmaf(v, v0.z, a0.z); a0.w = fmaf(v, v0.w, a0.w);
        a1.x = fmaf(v, v1.x, a1.x); a1.y = fmaf(v, v1.y, a1.y);
        a1.z = fmaf(v, v1.z, a1.z); a1.w = fmaf(v, v1.w, a1.w);
        a2.x = fmaf(v, v2.x, a2.x); a2.y = fmaf(v, v2.y, a2.y);
        a2.z = fmaf(v, v2.z, a2.z); a2.w = fmaf(v, v2.w, a2.w);
    }
    float* o = xa + (size_t)r * 768;
    *(float4*)(o + lane * 4) = a0;
    *(float4*)(o + 256 + lane * 4) = a1;
    *(float4*)(o + 512 + lane * 4) = a2;
}

// ---------------- one DWT level (pywt symmetric). in f32 or bf16; outD bf16; outA f32 or bf16 ----------------
template <bool IN_BF16, bool A_BF16>
__global__ void dwt_kernel(const void* __restrict__ in, int n, int in_stride,
                           void* __restrict__ outA, int a_stride,
                           unsigned short* __restrict__ outD, int d_stride, int m) {
    extern __shared__ float srow[];
    int row = blockIdx.x;
    if (IN_BF16) {
        const unsigned short* ip = (const unsigned short*)in + (size_t)row * in_stride;
        for (int i = threadIdx.x; i < n; i += blockDim.x) srow[i] = bf2f(ip[i]);
    } else {
        const float* ip = (const float*)in + (size_t)row * in_stride;
        for (int i = threadIdx.x; i < n; i += blockDim.x) srow[i] = ip[i];
    }
    __syncthreads();
    for (int j = threadIdx.x; j < m; j += blockDim.x) {
        float a = 0.f, d = 0.f;
#pragma unroll
        for (int i = 0; i < 8; ++i) {
            int p = 2 * j + 7 - i;
            int q = (p < 6) ? (5 - p) : ((p < n + 6) ? (p - 6) : (2 * n + 5 - p));
            float xv = srow[q];
            a = fmaf(c_LO[i], xv, a);
            d = fmaf(c_HI[i], xv, d);
        }
        if (A_BF16)
            ((unsigned short*)outA)[(size_t)row * a_stride + j] = f2bf(a);
        else
            ((float*)outA)[(size_t)row * a_stride + j] = a;
        outD[(size_t)row * d_stride + j] = f2bf(d);
    }
}

// ---------------- pack basis stack -> transposed bf16 [N][Kpad], zero-padded ----------------
struct Bounds { int b[6]; };

__global__ void pack_basis_T(const float* __restrict__ basis, unsigned short* __restrict__ BT,
                             Bounds bd, int brows, int N, int K, int Kpad) {
    int idx = blockIdx.x * blockDim.x + threadIdx.x;
    if (idx >= N * Kpad) return;
    int n = idx / Kpad, k = idx - n * Kpad;
    float v = 0.f;
    if (k < K) {
        int s = 0;
#pragma unroll
        for (int t = 1; t < 5; ++t)
            if (k >= bd.b[t]) s = t;
        int lr = k - bd.b[s];
        v = basis[((size_t)s * brows + lr) * N + n];
    }
    BT[idx] = f2bf(v);
}

// ---------------- pack weights [NB][K][N] -> transposed bf16 [NB][N][Kpad] ----------------
__global__ void pack_wT(const float* __restrict__ W, unsigned short* __restrict__ WT,
                        int NB, int K, int N, int Kpad) {
    int idx = blockIdx.x * blockDim.x + threadIdx.x;
    int tot = NB * N * Kpad;
    if (idx >= tot) return;
    int b = idx / (N * Kpad);
    int r = idx - b * (N * Kpad);
    int n = r / Kpad, k = r - n * Kpad;
    float v = (k < K) ? W[((size_t)b * K + k) * N + n] : 0.f;
    WT[idx] = f2bf(v);
}

// ---------------- bf16 MFMA GEMM: C[M,N] = A[M,Kpad] @ BT[N,Kpad]^T (+bias) ----------------
template <int OUT_BF16>
__global__ __launch_bounds__(256) void gemm_mfma(const unsigned short* __restrict__ A,
                                                 const unsigned short* __restrict__ BT,
                                                 const float* __restrict__ bias,
                                                 void* __restrict__ Cv,
                                                 int M, int N, int K, int lda, int ldb, int ldc) {
    __shared__ __align__(16) unsigned short As[128 * 32];
    __shared__ __align__(16) unsigned short Bs[128 * 32];
    const int tid = threadIdx.x;
    const int wave = tid >> 6, lane = tid & 63;
    const int m0 = blockIdx.y * 128, n0 = blockIdx.x * 128;
    const int wr = wave >> 1, wc = wave & 1;
    const int frow = lane & 15, fq = lane >> 4;

    const int off0 = tid * 16;
    const int r0 = off0 >> 6, c0 = off0 & 63;
    const int r1 = (off0 + 4096) >> 6, c1 = (off0 + 4096) & 63;
    const char* Ab = (const char*)A;
    const char* Bb = (const char*)BT;
    size_t gA0 = (size_t)(m0 + r0) * lda * 2 + c0;
    size_t gA1 = (size_t)(m0 + r1) * lda * 2 + c1;
    size_t gB0 = (size_t)(n0 + r0) * ldb * 2 + c0;
    size_t gB1 = (size_t)(n0 + r1) * ldb * 2 + c1;
    char* lA0 = (char*)As + wave * 1024;
    char* lB0 = (char*)Bs + wave * 1024;

    const int aoff = (wr * 64 + frow) * 32 + fq * 8;
    const int boff = (wc * 64 + frow) * 32 + fq * 8;

    float4v acc[4][4] = {};
    for (int k0 = 0; k0 < K; k0 += 32) {
        size_t kb2 = (size_t)k0 * 2;
        gload_lds16(Ab + gA0 + kb2, lA0);
        gload_lds16(Ab + gA1 + kb2, lA0 + 4096);
        gload_lds16(Bb + gB0 + kb2, lB0);
        gload_lds16(Bb + gB1 + kb2, lB0 + 4096);
        __syncthreads();
        short8v av[4], bv[4];
#pragma unroll
        for (int i = 0; i < 4; ++i) av[i] = *(const short8v*)(As + aoff + i * 512);
#pragma unroll
        for (int i = 0; i < 4; ++i) bv[i] = *(const short8v*)(Bs + boff + i * 512);
#pragma unroll
        for (int mi = 0; mi < 4; ++mi)
#pragma unroll
            for (int ni = 0; ni < 4; ++ni)
                acc[mi][ni] = __builtin_amdgcn_mfma_f32_16x16x32_bf16(av[mi], bv[ni], acc[mi][ni], 0, 0, 0);
        __syncthreads();
    }
#pragma unroll
    for (int ni = 0; ni < 4; ++ni) {
        int col = n0 + wc * 64 + ni * 16 + frow;
        float bval = bias ? bias[col] : 0.f;
#pragma unroll
        for (int mi = 0; mi < 4; ++mi) {
#pragma unroll
            for (int i = 0; i < 4; ++i) {
                int row = m0 + wr * 64 + mi * 16 + fq * 4 + i;
                float v = acc[mi][ni][i] + bval;
                if (OUT_BF16)
                    ((unsigned short*)Cv)[(size_t)row * ldc + col] = f2bf(v);
                else
                    ((float*)Cv)[(size_t)row * ldc + col] = v;
            }
        }
    }
}

// ---- dendritic partial: P = max_{kb in [kb0,kb0+kbn)} gelu(A @ WT[kb]^T + b[kb]), bf16 out ----
__global__ __launch_bounds__(256) void dendritic_partial(const unsigned short* __restrict__ A,
                                                         const unsigned short* __restrict__ WT,
                                                         const float* __restrict__ bias,
                                                         unsigned short* __restrict__ Pout,
                                                         int M, int N, int K, int nb, int ngrp) {
    __shared__ __align__(16) unsigned short As[128 * 32];
    __shared__ __align__(16) unsigned short Bs[128 * 32];
    const int tid = threadIdx.x;
    const int wave = tid >> 6, lane = tid & 63;
    const int m0 = blockIdx.y * 128, n0 = blockIdx.x * 128;
    const int wr = wave >> 1, wc = wave & 1;
    const int frow = lane & 15, fq = lane >> 4;

    // branch group [kb0, kb0+kbn)
    const int gz = blockIdx.z;
    const int q = nb / ngrp, rmd = nb - q * ngrp;
    const int kb0 = gz * q + (gz < rmd ? gz : rmd);
    const int kbn = q + (gz < rmd ? 1 : 0);
    unsigned short* P = Pout + (size_t)gz * M * N;

    const int off0 = tid * 16;
    const int r0 = off0 >> 6, c0 = off0 & 63;
    const int r1 = (off0 + 4096) >> 6, c1 = (off0 + 4096) & 63;
    const char* Ab = (const char*)A;
    size_t gA0 = (size_t)(m0 + r0) * K * 2 + c0;
    size_t gA1 = (size_t)(m0 + r1) * K * 2 + c1;
    size_t gB0 = (size_t)(n0 + r0) * K * 2 + c0;
    size_t gB1 = (size_t)(n0 + r1) * K * 2 + c1;
    char* lA0 = (char*)As + wave * 1024;
    char* lB0 = (char*)Bs + wave * 1024;

    const int aoff = (wr * 64 + frow) * 32 + fq * 8;
    const int boff = (wc * 64 + frow) * 32 + fq * 8;

    float4v best[4][4];
#pragma unroll
    for (int mi = 0; mi < 4; ++mi)
#pragma unroll
        for (int ni = 0; ni < 4; ++ni) best[mi][ni] = (float4v)(-1e30f);

    for (int kb = kb0; kb < kb0 + kbn; ++kb) {
        const char* Bb = (const char*)(WT + (size_t)kb * N * K);
        float4v acc[4][4] = {};
        for (int k0 = 0; k0 < K; k0 += 32) {
            size_t kb2 = (size_t)k0 * 2;
            gload_lds16(Ab + gA0 + kb2, lA0);
            gload_lds16(Ab + gA1 + kb2, lA0 + 4096);
            gload_lds16(Bb + gB0 + kb2, lB0);
            gload_lds16(Bb + gB1 + kb2, lB0 + 4096);
            __syncthreads();
            short8v av[4], bv[4];
#pragma unroll
            for (int i = 0; i < 4; ++i) av[i] = *(const short8v*)(As + aoff + i * 512);
#pragma unroll
            for (int i = 0; i < 4; ++i) bv[i] = *(const short8v*)(Bs + boff + i * 512);
#pragma unroll
            for (int mi = 0; mi < 4; ++mi)
#pragma unroll
                for (int ni = 0; ni < 4; ++ni)
                    acc[mi][ni] = __builtin_amdgcn_mfma_f32_16x16x32_bf16(av[mi], bv[ni], acc[mi][ni], 0, 0, 0);
            __syncthreads();
        }
#pragma unroll
        for (int ni = 0; ni < 4; ++ni) {
            int col = n0 + wc * 64 + ni * 16 + frow;
            float bval = bias[(size_t)kb * N + col];
#pragma unroll
            for (int mi = 0; mi < 4; ++mi) {
#pragma unroll
                for (int i = 0; i < 4; ++i) {
                    float v = acc[mi][ni][i] + bval;
                    float g = 0.5f * v * (1.0f + erff(v * 0.70710678118654752f));
                    best[mi][ni][i] = fmaxf(best[mi][ni][i], g);
                }
            }
        }
    }
#pragma unroll
    for (int ni = 0; ni < 4; ++ni) {
        int col = n0 + wc * 64 + ni * 16 + frow;
#pragma unroll
        for (int mi = 0; mi < 4; ++mi) {
#pragma unroll
            for (int i = 0; i < 4; ++i) {
                int row = m0 + wr * 64 + mi * 16 + fq * 4 + i;
                P[(size_t)row * N + col] = f2bf(best[mi][ni][i]);
            }
        }
    }
}

// ---------------- combine: out[i] = max_s P[s][i]  (bf16 in/out, 4 elems/thread) ----------------
__global__ void combine_max(const unsigned short* __restrict__ P, unsigned short* __restrict__ out,
                            size_t tileElems, int S) {
    size_t i = ((size_t)blockIdx.x * blockDim.x + threadIdx.x) * 4;
    if (i >= tileElems) return;
    ushort4 best = *(const ushort4*)(P + i);
    for (int s = 1; s < S; ++s) {
        ushort4 c = *(const ushort4*)(P + (size_t)s * tileElems + i);
        if (bf2f(c.x) > bf2f(best.x)) best.x = c.x;
        if (bf2f(c.y) > bf2f(best.y)) best.y = c.y;
        if (bf2f(c.z) > bf2f(best.z)) best.z = c.z;
        if (bf2f(c.w) > bf2f(best.w)) best.w = c.w;
    }
    *(ushort4*)(out + i) = best;
}

// ---------------- LayerNorm over H=512: f32 in -> bf16 out ----------------
__global__ __launch_bounds__(256) void layernorm_bf16(const float* __restrict__ h,
                                                      unsigned short* __restrict__ o,
                                                      const float* __restrict__ g,
                                                      const float* __restrict__ b) {
    int row = blockIdx.x;
    const float* p = h + (size_t)row * 512;
    int tid = threadIdx.x;
    float v0 = p[tid], v1 = p[tid + 256];
    float s = v0 + v1, sq = v0 * v0 + v1 * v1;
#pragma unroll
    for (int off = 32; off >= 1; off >>= 1) {
        s += __shfl_xor(s, off);
        sq += __shfl_xor(sq, off);
    }
    __shared__ float ls[4], lq[4];
    int wid = tid >> 6, lane = tid & 63;
    if (lane == 0) { ls[wid] = s; lq[wid] = sq; }
    __syncthreads();
    float ts = ls[0] + ls[1] + ls[2] + ls[3];
    float tq = lq[0] + lq[1] + lq[2] + lq[3];
    float mean = ts / 512.f;
    float var = tq / 512.f - mean * mean;
    float inv = rsqrtf(var + 1e-5f);
    unsigned short* op = o + (size_t)row * 512;
    op[tid] = f2bf((v0 - mean) * inv * g[tid] + b[tid]);
    op[tid + 256] = f2bf((v1 - mean) * inv * g[tid + 256] + b[tid + 256]);
}

// ---------------- z = mu + eps * exp(0.5*logvar)  -> bf16 ----------------
__global__ void z_kernel(const float* __restrict__ mu, const float* __restrict__ lv,
                         const float* __restrict__ eps, unsigned short* __restrict__ z, int n4) {
    int i = blockIdx.x * blockDim.x + threadIdx.x;
    if (i >= n4) return;
    float4 m = ((const float4*)mu)[i];
    float4 l = ((const float4*)lv)[i];
    float4 e = ((const float4*)eps)[i];
    ushort4 o;
    o.x = f2bf(m.x + e.x * expf(0.5f * l.x));
    o.y = f2bf(m.y + e.y * expf(0.5f * l.y));
    o.z = f2bf(m.z + e.z * expf(0.5f * l.z));
    o.w = f2bf(m.w + e.w * expf(0.5f * l.w));
    ((ushort4*)z)[i] = o;
}

extern "C" void kernel_launch(void* const* d_in, const int* in_sizes, int n_in,
                              void* d_out, int out_size, void* d_ws, size_t ws_size,
                              hipStream_t stream) {
    const float* x        = (const float*)d_in[0];
    const int*   arows    = (const int*)d_in[1];
    const int*   acols    = (const int*)d_in[2];
    const float* avals    = (const float*)d_in[3];
    const float* basisenc = (const float*)d_in[4];
    const float* ln_g     = (const float*)d_in[5];
    const float* ln_b     = (const float*)d_in[6];
    const float* Wd_enc   = (const float*)d_in[7];
    const float* bd_enc   = (const float*)d_in[8];
    const float* W_mu     = (const float*)d_in[9];
    const float* b_mu     = (const float*)d_in[10];
    const float* W_lv     = (const float*)d_in[11];
    const float* b_lv     = (const float*)d_in[12];
    const float* Wd_dec   = (const float*)d_in[13];
    const float* bd_dec   = (const float*)d_in[14];
    const float* basisdec = (const float*)d_in[15];
    const float* epsin    = (const float*)d_in[16];

    const int N = 16384;
    const int E = in_sizes[1];

    float* ws = (float*)d_ws;
    // region A (f32, 16384*768 = 50.33 MB): xa -> hF -> enc partials (4x bf16 [N,256]) -> dec partials (3x bf16 [N,512], exact fit) -> b1
    const size_t A0 = 0;
    // region B (u16, 16384*800): cenc -> [cdec (16384*544) | zb (16384*256)]
    const size_t B0 = A0 + (size_t)N * 768;
    // region C (f32, 16384*387): a1 -> [hbf u16 | encb u16] -> dec_bf16 u16 [N,512]
    const size_t C0 = B0 + (size_t)N * 400;
    // region D (f32, 16384*197): a2 -> b2
    const size_t D0 = C0 + (size_t)N * 387;
    // region E (f32, 16384*102): a3 -> b3
    const size_t E0 = D0 + (size_t)N * 197;
    // region F (u16 weights)
    const size_t F0 = E0 + (size_t)N * 102;
    // region G (CSR)
    const size_t G0 = F0 + 3100672;

    float* xa  = ws + A0;
    float* hF  = ws + A0;
    unsigned short* Penc = (unsigned short*)(ws + A0);  // 4 x N*256
    unsigned short* Pdec = (unsigned short*)(ws + A0);  // 3 x N*512
    float* b1 = ws + A0;                                // after partials dead
    unsigned short* cenc = (unsigned short*)(ws + B0);
    unsigned short* cdec = (unsigned short*)(ws + B0);
    unsigned short* zb   = cdec + (size_t)N * 544;
    float* a1 = ws + C0;
    unsigned short* hbf  = (unsigned short*)(ws + C0);
    unsigned short* encb = hbf + (size_t)N * 512;
    unsigned short* decb = (unsigned short*)(ws + C0);  // [N,512] bf16, after hbf dead
    float* a2 = ws + D0;
    float* b2 = ws + D0;
    float* a3 = ws + E0;
    float* b3 = ws + E0;
    unsigned short* wF = (unsigned short*)(ws + F0);
    unsigned short* BceT   = wF;                       // 512*800
    unsigned short* BcdT   = BceT + 512 * 800;         // 768*544
    unsigned short* WdencT = BcdT + 768 * 544;         // 20*256*512
    unsigned short* WddecT = WdencT + 20 * 256 * 512;  // 20*512*256
    unsigned short* WmuT   = WddecT + 20 * 512 * 256;  // 256*256
    unsigned short* WlvT   = WmuT + 256 * 256;
    int*   csr_cnt  = (int*)(ws + G0);
    int*   csr_offs = csr_cnt + N;
    int*   csr_cur  = csr_offs + N + 1;
    int*   csr_col  = csr_cur + N;
    float* csr_val  = (float*)(csr_col + E);

    float* out_recon = (float*)d_out;
    float* out_mu    = out_recon + (size_t)N * 768;
    float* out_lv    = out_mu + (size_t)N * 256;

    // --- packs (independent of spmm chain) ---
    {
        Bounds be = {{0, 54, 108, 210, 407, 794}};
        pack_basis_T<<<(512 * 800 + 255) / 256, 256, 0, stream>>>(basisenc, BceT, be, 768, 512, 794, 800);
        Bounds bdd = {{0, 38, 76, 146, 279, 538}};
        pack_basis_T<<<(768 * 544 + 255) / 256, 256, 0, stream>>>(basisdec, BcdT, bdd, 512, 768, 538, 544);
        pack_wT<<<(20 * 256 * 512 + 255) / 256, 256, 0, stream>>>(Wd_enc, WdencT, 20, 512, 256, 512);
        pack_wT<<<(20 * 512 * 256 + 255) / 256, 256, 0, stream>>>(Wd_dec, WddecT, 20, 256, 512, 256);
        pack_wT<<<(256 * 256 + 255) / 256, 256, 0, stream>>>(W_mu, WmuT, 1, 256, 256, 256);
        pack_wT<<<(256 * 256 + 255) / 256, 256, 0, stream>>>(W_lv, WlvT, 1, 256, 256, 256);
    }

    // 1) SpMM via device-built CSR (no output atomics)
    hipMemsetAsync(csr_cnt, 0, N * sizeof(int), stream);
    hipMemsetAsync(cenc, 0, (size_t)N * 800 * sizeof(unsigned short), stream);
    hist_kernel<<<(E + 255) / 256, 256, 0, stream>>>(arows, csr_cnt, E);
    scan_kernel<<<1, 1024, 0, stream>>>(csr_cnt, csr_offs, csr_cur, N, E);
    scatter_kernel<<<(E + 255) / 256, 256, 0, stream>>>(arows, acols, avals, csr_cur, csr_col, csr_val, E);
    spmm_csr<<<N / 4, 256, 0, stream>>>(x, csr_offs, csr_col, csr_val, xa);

    // 2) wavedec enc: 768->387->197->102->54 ; cenc cols [cA4(0)|cD4(54)|cD3(108)|cD2(210)|cD1(407)]
    dwt_kernel<false, false><<<N, 128, 768 * 4, stream>>>(xa, 768, 768, a1, 387, cenc + 407, 800, 387);
    dwt_kernel<false, false><<<N, 128, 387 * 4, stream>>>(a1, 387, 387, a2, 197, cenc + 210, 800, 197);
    dwt_kernel<false, false><<<N, 128, 197 * 4, stream>>>(a2, 197, 197, a3, 102, cenc + 108, 800, 102);
    dwt_kernel<false, true><<<N, 128, 102 * 4, stream>>>(a3, 102, 102, cenc + 0, 800, cenc + 54, 800, 54);

    // 3) h = cenc @ BceT^T  [16384,512], K=800  (xa dead -> hF in region A)
    gemm_mfma<0><<<dim3(512 / 128, N / 128), 256, 0, stream>>>(cenc, BceT, nullptr, hF, N, 512, 800, 800, 800, 512);

    // 4) layernorm -> bf16 (hbf in region C; a1 dead)
    layernorm_bf16<<<N, 256, 0, stream>>>(hF, hbf, ln_g, ln_b);

    // 5) enc: partial max over 4 branch-groups (hF dead -> Penc in region A), then combine -> encb
    dendritic_partial<<<dim3(2, N / 128, 4), 256, 0, stream>>>(hbf, WdencT, bd_enc, Penc, N, 256, 512, 20, 4);
    combine_max<<<((size_t)N * 256 / 4 + 255) / 256, 256, 0, stream>>>(Penc, encb, (size_t)N * 256, 4);

    // 6) mu / logvar (f32 out to d_out), K=256
    gemm_mfma<0><<<dim3(256 / 128, N / 128), 256, 0, stream>>>(encb, WmuT, b_mu, out_mu, N, 256, 256, 256, 256, 256);
    gemm_mfma<0><<<dim3(256 / 128, N / 128), 256, 0, stream>>>(encb, WlvT, b_lv, out_lv, N, 256, 256, 256, 256, 256);

    // 7) z -> bf16 (zb in region B)
    z_kernel<<<(N * 256 / 4 + 255) / 256, 256, 0, stream>>>(out_mu, out_lv, epsin, zb, N * 256 / 4);

    // 8) dec: partial max over 3 branch-groups (Penc dead -> Pdec region A), combine -> decb (C, hbf dead)
    dendritic_partial<<<dim3(4, N / 128, 3), 256, 0, stream>>>(zb, WddecT, bd_dec, Pdec, N, 512, 256, 20, 3);
    combine_max<<<((size_t)N * 512 / 4 + 255) / 256, 256, 0, stream>>>(Pdec, decb, (size_t)N * 512, 3);

    // 9) memset cdec pad, then wavedec dec: 512->259->133->70->38 ; cols [0|38|76|146|279]
    hipMemsetAsync(cdec, 0, (size_t)N * 544 * sizeof(unsigned short), stream);
    dwt_kernel<true, false><<<N, 128, 512 * 4, stream>>>(decb, 512, 512, b1, 259, cdec + 279, 544, 259);
    dwt_kernel<false, false><<<N, 128, 259 * 4, stream>>>(b1, 259, 259, b2, 133, cdec + 146, 544, 133);
    dwt_kernel<false, false><<<N, 128, 133 * 4, stream>>>(b2, 133, 133, b3, 70, cdec + 76, 544, 70);
    dwt_kernel<false, true><<<N, 128, 70 * 4, stream>>>(b3, 70, 70, cdec + 0, 544, cdec + 38, 544, 38);

    // 10) recon = cdec @ BcdT^T [16384,768], K=544
    gemm_mfma<0><<<dim3(768 / 128, N / 128), 256, 0, stream>>>(cdec, BcdT, nullptr, out_recon, N, 768, 544, 544, 544, 768);

    (void)ws_size; (void)out_size; (void)n_in;
}

// Round 5
// 908.657 us; speedup vs baseline: 1.4423x; 1.4423x over previous
//
#include <hip/hip_runtime.h>

typedef __attribute__((ext_vector_type(8))) short short8v;
typedef __attribute__((ext_vector_type(8))) unsigned short ushort8v;
typedef __attribute__((ext_vector_type(4))) float float4v;

__device__ __constant__ float c_LO[8] = {
    -0.010597401784997278f, 0.032883011666982945f, 0.030841381835986965f,
    -0.18703481171888114f, -0.02798376941698385f, 0.6308807679295904f,
    0.7148465705525415f, 0.23037781330885523f};
__device__ __constant__ float c_HI[8] = {
    -0.23037781330885523f, 0.7148465705525415f, -0.6308807679295904f,
    -0.02798376941698385f, 0.18703481171888114f, 0.030841381835986965f,
    -0.032883011666982945f, -0.010597401784997278f};

__device__ __forceinline__ unsigned short f2bf(float f) {
    unsigned u = __builtin_bit_cast(unsigned, f);
    unsigned r = u + 0x7fffu + ((u >> 16) & 1u);
    return (unsigned short)(r >> 16);
}
__device__ __forceinline__ float bf2f(unsigned short u) {
    return __builtin_bit_cast(float, (unsigned)u << 16);
}

// tanh-form GELU: x * sigmoid(2*0.79788456*(x+0.044715x^3)); one v_exp_f32 + rcp.
__device__ __forceinline__ float gelu_fast(float x) {
    float x3 = x * x * x;
    float y = fmaf(0.044715f, x3, x) * 0.7978845608028654f;
    float t = fminf(fmaxf(y * 2.8853900817779268f, -30.f), 30.f);  // 2y*log2(e)
    float e = exp2f(t);
    return x * e * __builtin_amdgcn_rcpf(e + 1.0f);
}

__device__ __forceinline__ void gload_lds16(const void* g, void* l) {
    __builtin_amdgcn_global_load_lds(g, l, 16, 0, 0);
}

// ---------------- CSR build: histogram ----------------
__global__ void hist_kernel(const int* __restrict__ rows, int* __restrict__ cnt, int E) {
    int i = blockIdx.x * blockDim.x + threadIdx.x;
    if (i < E) atomicAdd(&cnt[rows[i]], 1);
}

// ---------------- CSR build: single-block scan ----------------
__global__ __launch_bounds__(1024) void scan_kernel(const int* __restrict__ cnt, int* __restrict__ offs,
                                                    int* __restrict__ cursor, int Nrows, int E) {
    __shared__ int part[1024];
    int tid = threadIdx.x;
    const int per = Nrows / 1024;  // 16
    int base = tid * per;
    int local[16];
    int s = 0;
    for (int i = 0; i < per; ++i) { local[i] = s; s += cnt[base + i]; }
    part[tid] = s;
    __syncthreads();
    for (int off = 1; off < 1024; off <<= 1) {
        int v = part[tid];
        int w = (tid >= off) ? part[tid - off] : 0;
        __syncthreads();
        part[tid] = v + w;
        __syncthreads();
    }
    int pre = (tid == 0) ? 0 : part[tid - 1];
    for (int i = 0; i < per; ++i) {
        int o = pre + local[i];
        offs[base + i] = o;
        cursor[base + i] = o;
    }
    if (tid == 0) offs[Nrows] = E;
}

// ---------------- CSR build: scatter ----------------
__global__ void scatter_kernel(const int* __restrict__ rows, const int* __restrict__ cols,
                               const float* __restrict__ vals, int* __restrict__ cursor,
                               int* __restrict__ ccol, float* __restrict__ cval, int E) {
    int i = blockIdx.x * blockDim.x + threadIdx.x;
    if (i >= E) return;
    int r = rows[i];
    int p = atomicAdd(&cursor[r], 1);
    ccol[p] = cols[i];
    cval[p] = vals[i];
}

// ---------------- SpMM CSR: one wave per row ----------------
__global__ __launch_bounds__(256) void spmm_csr(const float* __restrict__ x, const int* __restrict__ offs,
                                                const int* __restrict__ ccol, const float* __restrict__ cval,
                                                float* __restrict__ xa) {
    int r = blockIdx.x * 4 + (threadIdx.x >> 6);
    int lane = threadIdx.x & 63;
    int s = offs[r], e = offs[r + 1];
    float4 a0 = {0, 0, 0, 0}, a1 = a0, a2 = a0;
    for (int j = s; j < e; ++j) {
        int c = ccol[j];
        float v = cval[j];
        const float* xr = x + (size_t)c * 768;
        float4 v0 = *(const float4*)(xr + lane * 4);
        float4 v1 = *(const float4*)(xr + 256 + lane * 4);
        float4 v2 = *(const float4*)(xr + 512 + lane * 4);
        a0.x = fmaf(v, v0.x, a0.x); a0.y = fmaf(v, v0.y, a0.y);
        a0.z = fmaf(v, v0.z, a0.z); a0.w = fmaf(v, v0.w, a0.w);
        a1.x = fmaf(v, v1.x, a1.x); a1.y = fmaf(v, v1.y, a1.y);
        a1.z = fmaf(v, v1.z, a1.z); a1.w = fmaf(v, v1.w, a1.w);
        a2.x = fmaf(v, v2.x, a2.x); a2.y = fmaf(v, v2.y, a2.y);
        a2.z = fmaf(v, v2.z, a2.z); a2.w = fmaf(v, v2.w, a2.w);
    }
    float* o = xa + (size_t)r * 768;
    *(float4*)(o + lane * 4) = a0;
    *(float4*)(o + 256 + lane * 4) = a1;
    *(float4*)(o + 512 + lane * 4) = a2;
}

// ---------------- one DWT level (pywt symmetric) ----------------
template <bool IN_BF16, bool A_BF16>
__global__ void dwt_kernel(const void* __restrict__ in, int n, int in_stride,
                           void* __restrict__ outA, int a_stride,
                           unsigned short* __restrict__ outD, int d_stride, int m) {
    extern __shared__ float srow[];
    int row = blockIdx.x;
    if (IN_BF16) {
        const unsigned short* ip = (const unsigned short*)in + (size_t)row * in_stride;
        for (int i = threadIdx.x; i < n; i += blockDim.x) srow[i] = bf2f(ip[i]);
    } else {
        const float* ip = (const float*)in + (size_t)row * in_stride;
        for (int i = threadIdx.x; i < n; i += blockDim.x) srow[i] = ip[i];
    }
    __syncthreads();
    for (int j = threadIdx.x; j < m; j += blockDim.x) {
        float a = 0.f, d = 0.f;
#pragma unroll
        for (int i = 0; i < 8; ++i) {
            int p = 2 * j + 7 - i;
            int q = (p < 6) ? (5 - p) : ((p < n + 6) ? (p - 6) : (2 * n + 5 - p));
            float xv = srow[q];
            a = fmaf(c_LO[i], xv, a);
            d = fmaf(c_HI[i], xv, d);
        }
        if (A_BF16)
            ((unsigned short*)outA)[(size_t)row * a_stride + j] = f2bf(a);
        else
            ((float*)outA)[(size_t)row * a_stride + j] = a;
        outD[(size_t)row * d_stride + j] = f2bf(d);
    }
}

// ---------------- pack basis stack -> transposed bf16 [N][Kpad] ----------------
struct Bounds { int b[6]; };

__global__ void pack_basis_T(const float* __restrict__ basis, unsigned short* __restrict__ BT,
                             Bounds bd, int brows, int N, int K, int Kpad) {
    int idx = blockIdx.x * blockDim.x + threadIdx.x;
    if (idx >= N * Kpad) return;
    int n = idx / Kpad, k = idx - n * Kpad;
    float v = 0.f;
    if (k < K) {
        int s = 0;
#pragma unroll
        for (int t = 1; t < 5; ++t)
            if (k >= bd.b[t]) s = t;
        int lr = k - bd.b[s];
        v = basis[((size_t)s * brows + lr) * N + n];
    }
    BT[idx] = f2bf(v);
}

// ---------------- pack weights [NB][K][N] -> transposed bf16 [NB][N][Kpad] ----------------
__global__ void pack_wT(const float* __restrict__ W, unsigned short* __restrict__ WT,
                        int NB, int K, int N, int Kpad) {
    int idx = blockIdx.x * blockDim.x + threadIdx.x;
    int tot = NB * N * Kpad;
    if (idx >= tot) return;
    int b = idx / (N * Kpad);
    int r = idx - b * (N * Kpad);
    int n = r / Kpad, k = r - n * Kpad;
    float v = (k < K) ? W[((size_t)b * K + k) * N + n] : 0.f;
    WT[idx] = f2bf(v);
}

// ---------------- bf16 MFMA GEMM: C[M,N] = A[M,Kpad] @ BT[N,Kpad]^T (+bias) ----------------
template <int OUT_BF16>
__global__ __launch_bounds__(256) void gemm_mfma(const unsigned short* __restrict__ A,
                                                 const unsigned short* __restrict__ BT,
                                                 const float* __restrict__ bias,
                                                 void* __restrict__ Cv,
                                                 int M, int N, int K, int lda, int ldb, int ldc) {
    __shared__ __align__(16) unsigned short As[128 * 32];
    __shared__ __align__(16) unsigned short Bs[128 * 32];
    const int tid = threadIdx.x;
    const int wave = tid >> 6, lane = tid & 63;
    const int m0 = blockIdx.y * 128, n0 = blockIdx.x * 128;
    const int wr = wave >> 1, wc = wave & 1;
    const int frow = lane & 15, fq = lane >> 4;

    const int off0 = tid * 16;
    const int r0 = off0 >> 6, c0 = off0 & 63;
    const int r1 = (off0 + 4096) >> 6, c1 = (off0 + 4096) & 63;
    const char* Ab = (const char*)A;
    const char* Bb = (const char*)BT;
    size_t gA0 = (size_t)(m0 + r0) * lda * 2 + c0;
    size_t gA1 = (size_t)(m0 + r1) * lda * 2 + c1;
    size_t gB0 = (size_t)(n0 + r0) * ldb * 2 + c0;
    size_t gB1 = (size_t)(n0 + r1) * ldb * 2 + c1;
    char* lA0 = (char*)As + wave * 1024;
    char* lB0 = (char*)Bs + wave * 1024;

    const int aoff = (wr * 64 + frow) * 32 + fq * 8;
    const int boff = (wc * 64 + frow) * 32 + fq * 8;

    float4v acc[4][4] = {};
    for (int k0 = 0; k0 < K; k0 += 32) {
        size_t kb2 = (size_t)k0 * 2;
        gload_lds16(Ab + gA0 + kb2, lA0);
        gload_lds16(Ab + gA1 + kb2, lA0 + 4096);
        gload_lds16(Bb + gB0 + kb2, lB0);
        gload_lds16(Bb + gB1 + kb2, lB0 + 4096);
        __syncthreads();
        short8v av[4], bv[4];
#pragma unroll
        for (int i = 0; i < 4; ++i) av[i] = *(const short8v*)(As + aoff + i * 512);
#pragma unroll
        for (int i = 0; i < 4; ++i) bv[i] = *(const short8v*)(Bs + boff + i * 512);
#pragma unroll
        for (int mi = 0; mi < 4; ++mi)
#pragma unroll
            for (int ni = 0; ni < 4; ++ni)
                acc[mi][ni] = __builtin_amdgcn_mfma_f32_16x16x32_bf16(av[mi], bv[ni], acc[mi][ni], 0, 0, 0);
        __syncthreads();
    }
#pragma unroll
    for (int ni = 0; ni < 4; ++ni) {
        int col = n0 + wc * 64 + ni * 16 + frow;
        float bval = bias ? bias[col] : 0.f;
#pragma unroll
        for (int mi = 0; mi < 4; ++mi) {
#pragma unroll
            for (int i = 0; i < 4; ++i) {
                int row = m0 + wr * 64 + mi * 16 + fq * 4 + i;
                float v = acc[mi][ni][i] + bval;
                if (OUT_BF16)
                    ((unsigned short*)Cv)[(size_t)row * ldc + col] = f2bf(v);
                else
                    ((float*)Cv)[(size_t)row * ldc + col] = v;
            }
        }
    }
}

// ---- dendritic fused: out = max_kb gelu(A @ WT[kb]^T + b[kb]); A-tile LDS-resident, B prefetch ----
// A: [M, KTILE] bf16 (lda=KTILE); WT: [nb][Nc][KTILE] bf16; out bf16 [M, Nc].
template <int KTILE>
__global__ __launch_bounds__(256) void dendritic_fused(const unsigned short* __restrict__ A,
                                                       const unsigned short* __restrict__ WT,
                                                       const float* __restrict__ bias,
                                                       unsigned short* __restrict__ out,
                                                       int Nc, int nb) {
    constexpr int KS = KTILE / 32;   // K-steps per branch
    constexpr int KB = KTILE * 2;    // A row bytes
    __shared__ __align__(16) unsigned short Atile[128 * KTILE];
    __shared__ __align__(16) unsigned short Bt[2][128 * 32];
    const int tid = threadIdx.x;
    const int wave = tid >> 6, lane = tid & 63;
    const int m0 = blockIdx.y * 128, n0 = blockIdx.x * 128;
    const int wr = wave >> 1, wc = wave & 1;
    const int frow = lane & 15, fq = lane >> 4;

    // ---- stage A tile (once) with 8-row XOR swizzle: byte col ^= (row&7)<<4 ----
    {
        constexpr int CPR = KTILE / 8;  // 16B chunks per row
#pragma unroll
        for (int i = 0; i < 128 * CPR / 256; ++i) {
            int ch = tid + i * 256;
            int row = ch / CPR;
            int cb = (ch - row * CPR) * 16;
            ushort8v v = *(const ushort8v*)(A + (size_t)(m0 + row) * KTILE + cb / 2);
            *(ushort8v*)((char*)Atile + row * KB + (cb ^ ((row & 7) << 4))) = v;
        }
    }

    // ---- B staging constants: linear LDS dest, source pre-swizzled (col ^= (row&3)<<4) ----
    const int off0 = tid * 16;
    const int brow0 = off0 >> 6, bcb0 = off0 & 63;
    const int off1 = off0 + 4096;
    const int brow1 = off1 >> 6, bcb1 = off1 & 63;
    const size_t bsrc0 = (size_t)(n0 + brow0) * KB + (bcb0 ^ ((brow0 & 3) << 4));
    const size_t bsrc1 = (size_t)(n0 + brow1) * KB + (bcb1 ^ ((brow1 & 3) << 4));
    const char* WTb = (const char*)WT;
    const size_t branchBytes = (size_t)Nc * KB;

    // prologue: stage B(t=0) into buf 0
    {
        char* db = (char*)&Bt[0][0] + wave * 1024;
        gload_lds16(WTb + bsrc0, db);
        gload_lds16(WTb + bsrc1, db + 4096);
    }
    __syncthreads();  // drains A ds_writes (lgkm) + B loads (vm)

    // fragment read offsets
    int raBy[4], rbBy[4];
#pragma unroll
    for (int mi = 0; mi < 4; ++mi) {
        int ra = wr * 64 + mi * 16 + frow;
        raBy[mi] = ra * KB;
    }
#pragma unroll
    for (int ni = 0; ni < 4; ++ni) {
        int rb = wc * 64 + ni * 16 + frow;
        rbBy[ni] = rb * 64 + ((fq * 16) ^ ((rb & 3) << 4));
    }

    float4v acc[4][4] = {};
    float4v best[4][4];
#pragma unroll
    for (int mi = 0; mi < 4; ++mi)
#pragma unroll
        for (int ni = 0; ni < 4; ++ni) best[mi][ni] = (float4v)(-1e30f);

    const int T = nb * KS;
    int buf = 0;
    for (int t = 0; t < T; ++t) {
        const int kb = t / KS, ks = t - kb * KS;
        if (t + 1 < T) {
            const int t1 = t + 1;
            const int kb1 = t1 / KS, ks1 = t1 - kb1 * KS;
            const char* Bb = WTb + (size_t)kb1 * branchBytes + (size_t)ks1 * 64;
            char* db = (char*)&Bt[buf ^ 1][0] + wave * 1024;
            gload_lds16(Bb + bsrc0, db);
            gload_lds16(Bb + bsrc1, db + 4096);
        }
        short8v av[4], bv[4];
        const int kcol = ks * 64 + fq * 16;
#pragma unroll
        for (int mi = 0; mi < 4; ++mi) {
            int ra = wr * 64 + mi * 16 + frow;
            av[mi] = *(const short8v*)((const char*)Atile + raBy[mi] + (kcol ^ ((ra & 7) << 4)));
        }
#pragma unroll
        for (int ni = 0; ni < 4; ++ni)
            bv[ni] = *(const short8v*)((const char*)&Bt[buf][0] + rbBy[ni]);
#pragma unroll
        for (int mi = 0; mi < 4; ++mi)
#pragma unroll
            for (int ni = 0; ni < 4; ++ni)
                acc[mi][ni] = __builtin_amdgcn_mfma_f32_16x16x32_bf16(av[mi], bv[ni], acc[mi][ni], 0, 0, 0);
        if (ks == KS - 1) {
#pragma unroll
            for (int ni = 0; ni < 4; ++ni) {
                int col = n0 + wc * 64 + ni * 16 + frow;
                float bval = bias[kb * Nc + col];
#pragma unroll
                for (int mi = 0; mi < 4; ++mi) {
#pragma unroll
                    for (int i = 0; i < 4; ++i) {
                        float v = acc[mi][ni][i] + bval;
                        best[mi][ni][i] = fmaxf(best[mi][ni][i], gelu_fast(v));
                        acc[mi][ni][i] = 0.f;
                    }
                }
            }
        }
        __syncthreads();  // drains prefetch; next iter flips buffers
        buf ^= 1;
    }

#pragma unroll
    for (int ni = 0; ni < 4; ++ni) {
        int col = n0 + wc * 64 + ni * 16 + frow;
#pragma unroll
        for (int mi = 0; mi < 4; ++mi) {
#pragma unroll
            for (int i = 0; i < 4; ++i) {
                int row = m0 + wr * 64 + mi * 16 + fq * 4 + i;
                out[(size_t)row * Nc + col] = f2bf(best[mi][ni][i]);
            }
        }
    }
}

// ---------------- LayerNorm over H=512: f32 in -> bf16 out ----------------
__global__ __launch_bounds__(256) void layernorm_bf16(const float* __restrict__ h,
                                                      unsigned short* __restrict__ o,
                                                      const float* __restrict__ g,
                                                      const float* __restrict__ b) {
    int row = blockIdx.x;
    const float* p = h + (size_t)row * 512;
    int tid = threadIdx.x;
    float v0 = p[tid], v1 = p[tid + 256];
    float s = v0 + v1, sq = v0 * v0 + v1 * v1;
#pragma unroll
    for (int off = 32; off >= 1; off >>= 1) {
        s += __shfl_xor(s, off);
        sq += __shfl_xor(sq, off);
    }
    __shared__ float ls[4], lq[4];
    int wid = tid >> 6, lane = tid & 63;
    if (lane == 0) { ls[wid] = s; lq[wid] = sq; }
    __syncthreads();
    float ts = ls[0] + ls[1] + ls[2] + ls[3];
    float tq = lq[0] + lq[1] + lq[2] + lq[3];
    float mean = ts / 512.f;
    float var = tq / 512.f - mean * mean;
    float inv = rsqrtf(var + 1e-5f);
    unsigned short* op = o + (size_t)row * 512;
    op[tid] = f2bf((v0 - mean) * inv * g[tid] + b[tid]);
    op[tid + 256] = f2bf((v1 - mean) * inv * g[tid + 256] + b[tid + 256]);
}

// ---------------- z = mu + eps * exp(0.5*logvar)  -> bf16 ----------------
__global__ void z_kernel(const float* __restrict__ mu, const float* __restrict__ lv,
                         const float* __restrict__ eps, unsigned short* __restrict__ z, int n4) {
    int i = blockIdx.x * blockDim.x + threadIdx.x;
    if (i >= n4) return;
    float4 m = ((const float4*)mu)[i];
    float4 l = ((const float4*)lv)[i];
    float4 e = ((const float4*)eps)[i];
    ushort4 o;
    o.x = f2bf(m.x + e.x * expf(0.5f * l.x));
    o.y = f2bf(m.y + e.y * expf(0.5f * l.y));
    o.z = f2bf(m.z + e.z * expf(0.5f * l.z));
    o.w = f2bf(m.w + e.w * expf(0.5f * l.w));
    ((ushort4*)z)[i] = o;
}

extern "C" void kernel_launch(void* const* d_in, const int* in_sizes, int n_in,
                              void* d_out, int out_size, void* d_ws, size_t ws_size,
                              hipStream_t stream) {
    const float* x        = (const float*)d_in[0];
    const int*   arows    = (const int*)d_in[1];
    const int*   acols    = (const int*)d_in[2];
    const float* avals    = (const float*)d_in[3];
    const float* basisenc = (const float*)d_in[4];
    const float* ln_g     = (const float*)d_in[5];
    const float* ln_b     = (const float*)d_in[6];
    const float* Wd_enc   = (const float*)d_in[7];
    const float* bd_enc   = (const float*)d_in[8];
    const float* W_mu     = (const float*)d_in[9];
    const float* b_mu     = (const float*)d_in[10];
    const float* W_lv     = (const float*)d_in[11];
    const float* b_lv     = (const float*)d_in[12];
    const float* Wd_dec   = (const float*)d_in[13];
    const float* bd_dec   = (const float*)d_in[14];
    const float* basisdec = (const float*)d_in[15];
    const float* epsin    = (const float*)d_in[16];

    const int N = 16384;
    const int E = in_sizes[1];

    float* ws = (float*)d_ws;
    // region A (f32, 16384*768): xa -> hF -> b1
    const size_t A0 = 0;
    // region B (u16, 16384*800): cenc -> [cdec (16384*544) | zb (16384*256)]
    const size_t B0 = A0 + (size_t)N * 768;
    // region C (f32, 16384*387): a1 -> [hbf u16 | encb u16] -> decb u16 [N,512]
    const size_t C0 = B0 + (size_t)N * 400;
    // region D (f32, 16384*197): a2 -> b2
    const size_t D0 = C0 + (size_t)N * 387;
    // region E (f32, 16384*102): a3 -> b3
    const size_t E0 = D0 + (size_t)N * 197;
    // region F (u16 weights)
    const size_t F0 = E0 + (size_t)N * 102;
    // region G (CSR)
    const size_t G0 = F0 + 3100672;

    float* xa  = ws + A0;
    float* hF  = ws + A0;
    float* b1  = ws + A0;
    unsigned short* cenc = (unsigned short*)(ws + B0);
    unsigned short* cdec = (unsigned short*)(ws + B0);
    unsigned short* zb   = cdec + (size_t)N * 544;
    float* a1 = ws + C0;
    unsigned short* hbf  = (unsigned short*)(ws + C0);
    unsigned short* encb = hbf + (size_t)N * 512;
    unsigned short* decb = (unsigned short*)(ws + C0);  // after hbf dead
    float* a2 = ws + D0;
    float* b2 = ws + D0;
    float* a3 = ws + E0;
    float* b3 = ws + E0;
    unsigned short* wF = (unsigned short*)(ws + F0);
    unsigned short* BceT   = wF;                       // 512*800
    unsigned short* BcdT   = BceT + 512 * 800;         // 768*544
    unsigned short* WdencT = BcdT + 768 * 544;         // 20*256*512
    unsigned short* WddecT = WdencT + 20 * 256 * 512;  // 20*512*256
    unsigned short* WmuT   = WddecT + 20 * 512 * 256;  // 256*256
    unsigned short* WlvT   = WmuT + 256 * 256;
    int*   csr_cnt  = (int*)(ws + G0);
    int*   csr_offs = csr_cnt + N;
    int*   csr_cur  = csr_offs + N + 1;
    int*   csr_col  = csr_cur + N;
    float* csr_val  = (float*)(csr_col + E);

    float* out_recon = (float*)d_out;
    float* out_mu    = out_recon + (size_t)N * 768;
    float* out_lv    = out_mu + (size_t)N * 256;

    // --- packs (independent of spmm chain) ---
    {
        Bounds be = {{0, 54, 108, 210, 407, 794}};
        pack_basis_T<<<(512 * 800 + 255) / 256, 256, 0, stream>>>(basisenc, BceT, be, 768, 512, 794, 800);
        Bounds bdd = {{0, 38, 76, 146, 279, 538}};
        pack_basis_T<<<(768 * 544 + 255) / 256, 256, 0, stream>>>(basisdec, BcdT, bdd, 512, 768, 538, 544);
        pack_wT<<<(20 * 256 * 512 + 255) / 256, 256, 0, stream>>>(Wd_enc, WdencT, 20, 512, 256, 512);
        pack_wT<<<(20 * 512 * 256 + 255) / 256, 256, 0, stream>>>(Wd_dec, WddecT, 20, 256, 512, 256);
        pack_wT<<<(256 * 256 + 255) / 256, 256, 0, stream>>>(W_mu, WmuT, 1, 256, 256, 256);
        pack_wT<<<(256 * 256 + 255) / 256, 256, 0, stream>>>(W_lv, WlvT, 1, 256, 256, 256);
    }

    // 1) SpMM via device-built CSR
    hipMemsetAsync(csr_cnt, 0, N * sizeof(int), stream);
    hipMemsetAsync(cenc, 0, (size_t)N * 800 * sizeof(unsigned short), stream);
    hist_kernel<<<(E + 255) / 256, 256, 0, stream>>>(arows, csr_cnt, E);
    scan_kernel<<<1, 1024, 0, stream>>>(csr_cnt, csr_offs, csr_cur, N, E);
    scatter_kernel<<<(E + 255) / 256, 256, 0, stream>>>(arows, acols, avals, csr_cur, csr_col, csr_val, E);
    spmm_csr<<<N / 4, 256, 0, stream>>>(x, csr_offs, csr_col, csr_val, xa);

    // 2) wavedec enc: 768->387->197->102->54 ; cenc cols [cA4(0)|cD4(54)|cD3(108)|cD2(210)|cD1(407)]
    dwt_kernel<false, false><<<N, 128, 768 * 4, stream>>>(xa, 768, 768, a1, 387, cenc + 407, 800, 387);
    dwt_kernel<false, false><<<N, 128, 387 * 4, stream>>>(a1, 387, 387, a2, 197, cenc + 210, 800, 197);
    dwt_kernel<false, false><<<N, 128, 197 * 4, stream>>>(a2, 197, 197, a3, 102, cenc + 108, 800, 102);
    dwt_kernel<false, true><<<N, 128, 102 * 4, stream>>>(a3, 102, 102, cenc + 0, 800, cenc + 54, 800, 54);

    // 3) h = cenc @ BceT^T  [16384,512], K=800
    gemm_mfma<0><<<dim3(512 / 128, N / 128), 256, 0, stream>>>(cenc, BceT, nullptr, hF, N, 512, 800, 800, 800, 512);

    // 4) layernorm -> bf16
    layernorm_bf16<<<N, 256, 0, stream>>>(hF, hbf, ln_g, ln_b);

    // 5) enc = max_kb gelu(hbf @ Wd_enc[kb]) -> bf16, fused (A-resident LDS)
    dendritic_fused<512><<<dim3(256 / 128, N / 128), 256, 0, stream>>>(hbf, WdencT, bd_enc, encb, 256, 20);

    // 6) mu / logvar (f32 out to d_out), K=256
    gemm_mfma<0><<<dim3(256 / 128, N / 128), 256, 0, stream>>>(encb, WmuT, b_mu, out_mu, N, 256, 256, 256, 256, 256);
    gemm_mfma<0><<<dim3(256 / 128, N / 128), 256, 0, stream>>>(encb, WlvT, b_lv, out_lv, N, 256, 256, 256, 256, 256);

    // 7) z -> bf16
    z_kernel<<<(N * 256 / 4 + 255) / 256, 256, 0, stream>>>(out_mu, out_lv, epsin, zb, N * 256 / 4);

    // 8) dec = max_kb gelu(zb @ Wd_dec[kb]) -> bf16, fused
    dendritic_fused<256><<<dim3(512 / 128, N / 128), 256, 0, stream>>>(zb, WddecT, bd_dec, decb, 512, 20);

    // 9) memset cdec pad, then wavedec dec: 512->259->133->70->38 ; cols [0|38|76|146|279]
    hipMemsetAsync(cdec, 0, (size_t)N * 544 * sizeof(unsigned short), stream);
    dwt_kernel<true, false><<<N, 128, 512 * 4, stream>>>(decb, 512, 512, b1, 259, cdec + 279, 544, 259);
    dwt_kernel<false, false><<<N, 128, 259 * 4, stream>>>(b1, 259, 259, b2, 133, cdec + 146, 544, 133);
    dwt_kernel<false, false><<<N, 128, 133 * 4, stream>>>(b2, 133, 133, b3, 70, cdec + 76, 544, 70);
    dwt_kernel<false, true><<<N, 128, 70 * 4, stream>>>(b3, 70, 70, cdec + 0, 544, cdec + 38, 544, 38);

    // 10) recon = cdec @ BcdT^T [16384,768], K=544
    gemm_mfma<0><<<dim3(768 / 128, N / 128), 256, 0, stream>>>(cdec, BcdT, nullptr, out_recon, N, 768, 544, 544, 544, 768);

    (void)ws_size; (void)out_size; (void)n_in;
}